// Round 1
// baseline (858.883 us; speedup 1.0000x reference)
//
#include <hip/hip_runtime.h>
#include <cstdint>
#include <cstddef>

typedef __bf16 bf16_t;
typedef __bf16 bf16x8 __attribute__((ext_vector_type(8)));
typedef float  f32x4  __attribute__((ext_vector_type(4)));

#define S_LEN   2048
#define E_DIM   512
#define H_NUM   8
#define DH      64
#define MLP_DIM 2048

static __device__ __forceinline__ unsigned short f2bfu(float f){
  bf16_t h = (bf16_t)f;
  return __builtin_bit_cast(unsigned short, h);
}

static __device__ __forceinline__ float gelu_f(float v){
  return 0.5f*v*(1.0f + erff(v*0.70710678118654752f));
}

// ---------------- fp32 -> bf16 convert (plain) ----------------
__global__ __launch_bounds__(256) void cvt_kernel(const float* __restrict__ s,
                                                  bf16_t* __restrict__ d, int n){
  int i = (blockIdx.x*256 + threadIdx.x)*4;
  if (i < n){
    float4 v = *(const float4*)(s + i);
    ushort4 pk;
    pk.x = f2bfu(v.x); pk.y = f2bfu(v.y); pk.z = f2bfu(v.z); pk.w = f2bfu(v.w);
    *(ushort4*)((unsigned short*)d + i) = pk;
  }
}

// ---------------- fp32 -> split (hi+lo) bf16 convert ----------------
__global__ __launch_bounds__(256) void cvt_split_kernel(const float* __restrict__ s,
                                                        bf16_t* __restrict__ dh,
                                                        bf16_t* __restrict__ dl, int n){
  int i = (blockIdx.x*256 + threadIdx.x)*4;
  if (i < n){
    float4 v = *(const float4*)(s + i);
    float xs[4] = {v.x, v.y, v.z, v.w};
    ushort4 ph, pl;
    unsigned short* hp = (unsigned short*)&ph;
    unsigned short* lp = (unsigned short*)&pl;
    #pragma unroll
    for (int j=0;j<4;j++){
      bf16_t hi = (bf16_t)xs[j];
      bf16_t lo = (bf16_t)(xs[j] - (float)hi);
      hp[j] = __builtin_bit_cast(unsigned short, hi);
      lp[j] = __builtin_bit_cast(unsigned short, lo);
    }
    *(ushort4*)((unsigned short*)dh + i) = ph;
    *(ushort4*)((unsigned short*)dl + i) = pl;
  }
}

// ---------------- LayerNorm (plain bf16 out): one wave per row ----------------
__global__ __launch_bounds__(256) void ln_kernel(const float* __restrict__ x,
                                                 const float* __restrict__ w,
                                                 const float* __restrict__ bb,
                                                 bf16_t* __restrict__ out){
  const int row  = blockIdx.x*4 + (threadIdx.x>>6);
  const int lane = threadIdx.x & 63;
  const float* xr = x + (size_t)row*E_DIM + lane*8;
  float4 v0 = *(const float4*)xr;
  float4 v1 = *(const float4*)(xr + 4);
  float xs[8] = {v0.x, v0.y, v0.z, v0.w, v1.x, v1.y, v1.z, v1.w};
  float s = 0.f, s2 = 0.f;
  #pragma unroll
  for (int j=0;j<8;j++){ s += xs[j]; s2 += xs[j]*xs[j]; }
  #pragma unroll
  for (int off=1; off<64; off<<=1){
    s  += __shfl_xor(s,  off, 64);
    s2 += __shfl_xor(s2, off, 64);
  }
  float mean = s*(1.f/512.f);
  float var  = s2*(1.f/512.f) - mean*mean;
  float rstd = rsqrtf(fmaxf(var, 0.f) + 1e-5f);
  const float* wp = w  + lane*8;
  const float* bp = bb + lane*8;
  bf16x8 ov;
  #pragma unroll
  for (int j=0;j<8;j++)
    ov[j] = (bf16_t)((xs[j]-mean)*rstd*wp[j] + bp[j]);
  *(bf16x8*)(out + (size_t)row*E_DIM + lane*8) = ov;
}

// ---------------- LayerNorm with split hi/lo bf16 output ----------------
__global__ __launch_bounds__(256) void ln_split_kernel(const float* __restrict__ x,
                                                       const float* __restrict__ w,
                                                       const float* __restrict__ bb,
                                                       bf16_t* __restrict__ oh,
                                                       bf16_t* __restrict__ ol){
  const int row  = blockIdx.x*4 + (threadIdx.x>>6);
  const int lane = threadIdx.x & 63;
  const float* xr = x + (size_t)row*E_DIM + lane*8;
  float4 v0 = *(const float4*)xr;
  float4 v1 = *(const float4*)(xr + 4);
  float xs[8] = {v0.x, v0.y, v0.z, v0.w, v1.x, v1.y, v1.z, v1.w};
  float s = 0.f, s2 = 0.f;
  #pragma unroll
  for (int j=0;j<8;j++){ s += xs[j]; s2 += xs[j]*xs[j]; }
  #pragma unroll
  for (int off=1; off<64; off<<=1){
    s  += __shfl_xor(s,  off, 64);
    s2 += __shfl_xor(s2, off, 64);
  }
  float mean = s*(1.f/512.f);
  float var  = s2*(1.f/512.f) - mean*mean;
  float rstd = rsqrtf(fmaxf(var, 0.f) + 1e-5f);
  const float* wp = w  + lane*8;
  const float* bp = bb + lane*8;
  bf16x8 vh, vl;
  #pragma unroll
  for (int j=0;j<8;j++){
    float v = (xs[j]-mean)*rstd*wp[j] + bp[j];
    bf16_t hi = (bf16_t)v;
    vh[j] = hi;
    vl[j] = (bf16_t)(v - (float)hi);
  }
  size_t o = (size_t)row*E_DIM + lane*8;
  *(bf16x8*)(oh + o) = vh;
  *(bf16x8*)(ol + o) = vl;
}

// ---------------- split-precision QKV GEMM ----------------
__global__ __launch_bounds__(256) void gemm_qkv_split(
    const bf16_t* __restrict__ Ah, const bf16_t* __restrict__ Al,
    const bf16_t* __restrict__ Bh, const bf16_t* __restrict__ Bl,
    const float* __restrict__ bias,
    bf16_t* __restrict__ qh, bf16_t* __restrict__ ql,
    bf16_t* __restrict__ kh, bf16_t* __restrict__ kl,
    bf16_t* __restrict__ vtmp)
{
  constexpr int TM = 128, TN = 64, BK = 64, MI = 4, NI = 2;
  const int K = 512;

  __shared__ bf16_t Ahs[TM*BK], Als[TM*BK];
  __shared__ bf16_t Bhs[TN*BK], Bls[TN*BK];

  const int tid  = threadIdx.x;
  const int wave = tid>>6, lane = tid&63, quad = lane>>4, l16 = lane&15;
  const int wm = wave>>1, wn = wave&1;

  const int nblk = 1536/TN;
  const int bm = blockIdx.x / nblk;
  const int bn = blockIdx.x % nblk;
  const int m0 = bm*TM, n0 = bn*TN;

  f32x4 acc[MI][NI];
  #pragma unroll
  for (int i=0;i<MI;i++)
    #pragma unroll
    for (int j=0;j<NI;j++)
      acc[i][j] = (f32x4){0.f,0.f,0.f,0.f};

  for (int k0 = 0; k0 < K; k0 += BK){
    bf16x8 avh[4], avl[4], bvh[2], bvl[2];
    #pragma unroll
    for (int i=0;i<4;i++){
      int ga = tid + i*256;
      int row = ga>>3, c8 = (ga&7) ^ (row&7);
      size_t off = (size_t)(m0+row)*K + k0 + c8*8;
      avh[i] = *(const bf16x8*)(Ah + off);
      avl[i] = *(const bf16x8*)(Al + off);
    }
    #pragma unroll
    for (int i=0;i<2;i++){
      int gb = tid + i*256;
      int row = gb>>3, c8 = (gb&7) ^ (row&7);
      size_t off = (size_t)(n0+row)*K + k0 + c8*8;
      bvh[i] = *(const bf16x8*)(Bh + off);
      bvl[i] = *(const bf16x8*)(Bl + off);
    }
    __syncthreads();
    #pragma unroll
    for (int i=0;i<4;i++){
      *(bf16x8*)(Ahs + (size_t)(tid + i*256)*8) = avh[i];
      *(bf16x8*)(Als + (size_t)(tid + i*256)*8) = avl[i];
    }
    #pragma unroll
    for (int i=0;i<2;i++){
      *(bf16x8*)(Bhs + (size_t)(tid + i*256)*8) = bvh[i];
      *(bf16x8*)(Bls + (size_t)(tid + i*256)*8) = bvl[i];
    }
    __syncthreads();
    #pragma unroll
    for (int ks=0;ks<2;ks++){
      bf16x8 afh[MI], afl[MI], bfh[NI], bfl[NI];
      #pragma unroll
      for (int mi=0;mi<MI;mi++){
        int rm = wm*64 + mi*16 + l16;
        size_t sl = (size_t)(rm*8 + ((ks*4+quad) ^ (rm&7)))*8;
        afh[mi] = *(const bf16x8*)(Ahs + sl);
        afl[mi] = *(const bf16x8*)(Als + sl);
      }
      #pragma unroll
      for (int ni=0;ni<NI;ni++){
        int rn = wn*32 + ni*16 + l16;
        size_t sl = (size_t)(rn*8 + ((ks*4+quad) ^ (rn&7)))*8;
        bfh[ni] = *(const bf16x8*)(Bhs + sl);
        bfl[ni] = *(const bf16x8*)(Bls + sl);
      }
      #pragma unroll
      for (int mi=0;mi<MI;mi++)
        #pragma unroll
        for (int ni=0;ni<NI;ni++){
          acc[mi][ni] = __builtin_amdgcn_mfma_f32_16x16x32_bf16(afh[mi], bfh[ni], acc[mi][ni], 0,0,0);
          acc[mi][ni] = __builtin_amdgcn_mfma_f32_16x16x32_bf16(afl[mi], bfh[ni], acc[mi][ni], 0,0,0);
          acc[mi][ni] = __builtin_amdgcn_mfma_f32_16x16x32_bf16(afh[mi], bfl[ni], acc[mi][ni], 0,0,0);
        }
    }
  }

  #pragma unroll
  for (int mi=0;mi<MI;mi++){
    const int grow0 = m0 + wm*64 + mi*16 + quad*4;
    #pragma unroll
    for (int ni=0;ni<NI;ni++){
      const int gcol = n0 + wn*32 + ni*16 + l16;
      const float bvx = bias[gcol];
      if (gcol < 512){
        #pragma unroll
        for (int r=0;r<4;r++){
          float v = acc[mi][ni][r] + bvx;
          size_t idx = (size_t)(grow0+r)*E_DIM + gcol;
          bf16_t hi = (bf16_t)v;
          qh[idx] = hi;
          ql[idx] = (bf16_t)(v - (float)hi);
        }
      } else if (gcol < 1024){
        const int cc = gcol - 512;
        #pragma unroll
        for (int r=0;r<4;r++){
          float v = acc[mi][ni][r] + bvx;
          size_t idx = (size_t)(grow0+r)*E_DIM + cc;
          bf16_t hi = (bf16_t)v;
          kh[idx] = hi;
          kl[idx] = (bf16_t)(v - (float)hi);
        }
      } else {
        const int cc = gcol - 1024;
        #pragma unroll
        for (int r=0;r<4;r++)
          vtmp[(size_t)(grow0+r)*E_DIM + cc] = (bf16_t)(acc[mi][ni][r] + bvx);
      }
    }
  }
}

// ---------------- V transpose: (B,S,E) flat -> vt[i][d][t] ----------------
__global__ __launch_bounds__(256) void vtrans_kernel(const bf16_t* __restrict__ v,
                                                     bf16_t* __restrict__ vt){
  __shared__ bf16_t tile[32*516];
  const int ic = blockIdx.x >> 3;
  const int rg = blockIdx.x & 7;
  const int tid = threadIdx.x;
  const size_t src = ((size_t)ic*256 + rg*32)*E_DIM;
  #pragma unroll
  for (int j=0;j<8;j++){
    int idx = j*2048 + tid*8;
    int row = idx >> 9, col = idx & 511;
    *(bf16x8*)(tile + row*516 + col) = *(const bf16x8*)(v + src + idx);
  }
  __syncthreads();
  #pragma unroll
  for (int j=0;j<8;j++){
    int idx = j*2048 + tid*8;
    int d = idx >> 8;
    int toff = idx & 255;
    int row = toff >> 3;
    bf16x8 o;
    #pragma unroll
    for (int jj=0;jj<8;jj++)
      o[jj] = tile[row*516 + jj*64 + d];
    *(bf16x8*)(vt + ((size_t)ic*64 + d)*S_LEN + rg*256 + toff) = o;
  }
}

// ---------------- plain bf16 GEMM ----------------
template<int TN, int MODE>
__global__ __launch_bounds__(256) void gemm_kernel(
    const bf16_t* __restrict__ A, const bf16_t* __restrict__ Bw,
    const float* __restrict__ bias, int M, int N, int K,
    void* out0, const float* __restrict__ resid)
{
  constexpr int TM = 128;
  constexpr int BK = 64;
  constexpr int MI = 4;
  constexpr int NI = TN/32;
  constexpr int GB = TN/32;

  __shared__ bf16_t As[TM*BK];
  __shared__ bf16_t Bs[TN*BK];

  const int tid  = threadIdx.x;
  const int wave = tid>>6, lane = tid&63, quad = lane>>4, l16 = lane&15;
  const int wm = wave>>1, wn = wave&1;

  const int nblk = N / TN;
  const int bm = blockIdx.x / nblk;
  const int bn = blockIdx.x % nblk;
  const int m0 = bm*TM, n0 = bn*TN;

  f32x4 acc[MI][NI];
  #pragma unroll
  for (int i=0;i<MI;i++)
    #pragma unroll
    for (int j=0;j<NI;j++)
      acc[i][j] = (f32x4){0.f,0.f,0.f,0.f};

  for (int k0 = 0; k0 < K; k0 += BK){
    bf16x8 av[4];
    #pragma unroll
    for (int i=0;i<4;i++){
      int ga = tid + i*256;
      int row = ga>>3, c8 = (ga&7) ^ (row&7);
      av[i] = *(const bf16x8*)(A + (size_t)(m0+row)*K + k0 + c8*8);
    }
    bf16x8 bv[GB];
    #pragma unroll
    for (int i=0;i<GB;i++){
      int gb = tid + i*256;
      int row = gb>>3, c8 = (gb&7) ^ (row&7);
      bv[i] = *(const bf16x8*)(Bw + (size_t)(n0+row)*K + k0 + c8*8);
    }
    __syncthreads();
    #pragma unroll
    for (int i=0;i<4;i++)  *(bf16x8*)(As + (size_t)(tid + i*256)*8) = av[i];
    #pragma unroll
    for (int i=0;i<GB;i++) *(bf16x8*)(Bs + (size_t)(tid + i*256)*8) = bv[i];
    __syncthreads();
    #pragma unroll
    for (int ks=0;ks<2;ks++){
      bf16x8 af[MI], bfr[NI];
      #pragma unroll
      for (int mi=0;mi<MI;mi++){
        int rm = wm*64 + mi*16 + l16;
        af[mi] = *(const bf16x8*)(As + (size_t)(rm*8 + ((ks*4+quad) ^ (rm&7)))*8);
      }
      #pragma unroll
      for (int ni=0;ni<NI;ni++){
        int rn = wn*(TN/2) + ni*16 + l16;
        bfr[ni] = *(const bf16x8*)(Bs + (size_t)(rn*8 + ((ks*4+quad) ^ (rn&7)))*8);
      }
      #pragma unroll
      for (int mi=0;mi<MI;mi++)
        #pragma unroll
        for (int ni=0;ni<NI;ni++)
          acc[mi][ni] = __builtin_amdgcn_mfma_f32_16x16x32_bf16(af[mi], bfr[ni], acc[mi][ni], 0,0,0);
    }
  }

  #pragma unroll
  for (int mi=0;mi<MI;mi++){
    const int grow0 = m0 + wm*64 + mi*16 + quad*4;
    #pragma unroll
    for (int ni=0;ni<NI;ni++){
      const int gcol = n0 + wn*(TN/2) + ni*16 + l16;
      const float bvx = bias[gcol];
      if constexpr (MODE==1){
        float* xo = (float*)out0;
        #pragma unroll
        for (int r=0;r<4;r++){
          size_t idx = (size_t)(grow0+r)*E_DIM + gcol;
          xo[idx] = resid[idx] + acc[mi][ni][r] + bvx;
        }
      } else if constexpr (MODE==2){
        bf16_t* hp = (bf16_t*)out0;
        #pragma unroll
        for (int r=0;r<4;r++)
          hp[(size_t)(grow0+r)*MLP_DIM + gcol] = (bf16_t)gelu_f(acc[mi][ni][r] + bvx);
      } else {
        float* xo = (float*)out0;
        #pragma unroll
        for (int r=0;r<4;r++){
          size_t idx = (size_t)(grow0+r)*E_DIM + gcol;
          xo[idx] = xo[idx] + acc[mi][ni][r] + bvx;
        }
      }
    }
  }
}

// ---------------- fused attention: one block = (b, 16 q-rows), loops 8 heads ----------------
// Gate applied OUTSIDE the MFMA fragment domain: pass1 writes raw scores to
// swizzled LDS; pass1.5 multiplies by gate held in registers (prefetched one
// head ahead via coalesced f32x4 NT loads) and does per-row fp64 sum + max/min
// with one wave per row. aw head-mean kept in 32 VGPRs -> f32x4 NT stores.
__global__ __launch_bounds__(1024) void attn_kernel(
    const bf16_t* __restrict__ qhb, const bf16_t* __restrict__ qlb,
    const bf16_t* __restrict__ khb, const bf16_t* __restrict__ klb,
    const bf16_t* __restrict__ vt,  const float* __restrict__ gate,
    bf16_t* __restrict__ og, float* __restrict__ aw)
{
  __shared__ __align__(16) float u_s[16*2048];   // 131072 B, float4-XOR swizzled
  __shared__ float osh[16*64];
  __shared__ float zsh[16];
  __shared__ float invr_sh[16];
  __shared__ float msh[16];

  const int b   = blockIdx.x >> 7;
  const int sqt = blockIdx.x & 127;
  const int sq0 = sqt*16;

  const int tid = threadIdx.x;
  const int wave = tid>>6, lane = tid&63, quad = lane>>4, l16 = lane&15;

  float awacc[32];
  #pragma unroll
  for (int j=0;j<32;j++) awacc[j] = 0.f;

  // gate prefetch for head 0: wave = row, thread covers cols {it*256 + lane*4 .. +3}
  f32x4 gpre[8];
  {
    const float* gp = gate + ((size_t)(b*H_NUM)*S_LEN + sq0 + wave)*S_LEN + (size_t)lane*4;
    #pragma unroll
    for (int it=0; it<8; it++)
      gpre[it] = __builtin_nontemporal_load((const f32x4*)(gp + it*256));
  }

  for (int h = 0; h < H_NUM; h++){
    const int bh = b*H_NUM + h;

    osh[tid] = 0.f;
    if (tid < 16) zsh[tid] = 0.f;

    bf16x8 qah0, qah1, qal0, qal1;
    {
      const size_t qoff = ((size_t)bh*S_LEN + sq0 + l16)*DH + quad*8;
      qah0 = *(const bf16x8*)(qhb + qoff);
      qah1 = *(const bf16x8*)(qhb + qoff + 32);
      qal0 = *(const bf16x8*)(qlb + qoff);
      qal1 = *(const bf16x8*)(qlb + qoff + 32);
    }

    // ---- pass 1: raw scores s = q.k^T -> swizzled LDS (no gate, no reductions)
    for (int cb = wave; cb < 32; cb += 16){
      #pragma unroll
      for (int nb=0; nb<4; nb++){
        const int col0 = cb*64 + nb*16;
        const size_t koff = ((size_t)bh*S_LEN + col0 + l16)*DH + quad*8;
        bf16x8 khf0 = *(const bf16x8*)(khb + koff);
        bf16x8 khf1 = *(const bf16x8*)(khb + koff + 32);
        bf16x8 klf0 = *(const bf16x8*)(klb + koff);
        bf16x8 klf1 = *(const bf16x8*)(klb + koff + 32);
        f32x4 acc = (f32x4){0.f,0.f,0.f,0.f};
        acc = __builtin_amdgcn_mfma_f32_16x16x32_bf16(qah0, khf0, acc, 0,0,0);
        acc = __builtin_amdgcn_mfma_f32_16x16x32_bf16(qah1, khf1, acc, 0,0,0);
        acc = __builtin_amdgcn_mfma_f32_16x16x32_bf16(qal0, khf0, acc, 0,0,0);
        acc = __builtin_amdgcn_mfma_f32_16x16x32_bf16(qal1, khf1, acc, 0,0,0);
        acc = __builtin_amdgcn_mfma_f32_16x16x32_bf16(qah0, klf0, acc, 0,0,0);
        acc = __builtin_amdgcn_mfma_f32_16x16x32_bf16(qah1, klf1, acc, 0,0,0);
        const int c = col0 + l16;
        #pragma unroll
        for (int r=0;r<4;r++){
          const int row = quad*4 + r;
          u_s[row*2048 + (c ^ ((row&7)<<2))] = acc[r];
        }
      }
    }
    __syncthreads();

    // ---- pass 1.5: u = s*gate (gate from regs); fp64 row sum + max/min, 1 wave = 1 row
    {
      f32x4* ub = (f32x4*)u_s + (size_t)wave*512;
      const int sw = wave & 7;
      double s = 0.0;
      float mx = -__builtin_inff(), mn = __builtin_inff();
      #pragma unroll
      for (int it=0; it<8; it++){
        const int c4 = (it*64 + lane) ^ sw;
        f32x4 u = ub[c4];
        u = u * gpre[it];
        ub[c4] = u;
        s += ((double)u[0] + (double)u[1]) + ((double)u[2] + (double)u[3]);
        mx = fmaxf(mx, fmaxf(fmaxf(u[0],u[1]), fmaxf(u[2],u[3])));
        mn = fminf(mn, fminf(fminf(u[0],u[1]), fminf(u[2],u[3])));
      }
      // prefetch gate for next head; latency hidden under pass2/3 + next pass1
      if (h + 1 < H_NUM){
        const float* gp = gate + ((size_t)(b*H_NUM + h + 1)*S_LEN + sq0 + wave)*S_LEN + (size_t)lane*4;
        #pragma unroll
        for (int it=0; it<8; it++)
          gpre[it] = __builtin_nontemporal_load((const f32x4*)(gp + it*256));
      }
      #pragma unroll
      for (int off=1; off<64; off<<=1){
        s  += __shfl_xor(s, off, 64);
        mx = fmaxf(mx, __shfl_xor(mx, off, 64));
        mn = fminf(mn, __shfl_xor(mn, off, 64));
      }
      if (lane == 0){
        double rsum = s + 1e-12;
        float inv = (float)(1.0/rsum);
        invr_sh[wave] = inv;
        msh[wave] = (rsum > 0.0 ? mx : mn) * inv;   // exact max of u*inv -> max e == 1
      }
    }
    __syncthreads();

    // ---- pass 2: e = exp(u*inv - m); z; o = e @ V  (16 waves: nb2 x k-quarter)
    const float inv_r = invr_sh[l16];
    const float m_v   = msh[l16];
    const int nb2 = wave & 3, kh2 = wave >> 2;
    f32x4 oacc = (f32x4){0.f,0.f,0.f,0.f};
    float zp = 0.f;
    const bf16_t* vbase = vt + ((size_t)bh*DH + nb2*16 + l16)*S_LEN;
    const f32x4* ur4 = (const f32x4*)u_s + (size_t)l16*512;
    const int swr = l16 & 7;
    for (int kc = kh2*16; kc < kh2*16 + 16; kc++){
      const int c4a = kc*8 + quad*2;
      f32x4 u0 = ur4[c4a ^ swr];
      f32x4 u1 = ur4[(c4a+1) ^ swr];
      float e0 = __expf(u0[0]*inv_r - m_v);
      float e1 = __expf(u0[1]*inv_r - m_v);
      float e2 = __expf(u0[2]*inv_r - m_v);
      float e3 = __expf(u0[3]*inv_r - m_v);
      float e4 = __expf(u1[0]*inv_r - m_v);
      float e5 = __expf(u1[1]*inv_r - m_v);
      float e6 = __expf(u1[2]*inv_r - m_v);
      float e7 = __expf(u1[3]*inv_r - m_v);
      if (nb2 == 0) zp += ((e0+e1)+(e2+e3)) + ((e4+e5)+(e6+e7));
      bf16x8 pa;
      pa[0]=(bf16_t)e0; pa[1]=(bf16_t)e1; pa[2]=(bf16_t)e2; pa[3]=(bf16_t)e3;
      pa[4]=(bf16_t)e4; pa[5]=(bf16_t)e5; pa[6]=(bf16_t)e6; pa[7]=(bf16_t)e7;
      bf16x8 vf = *(const bf16x8*)(vbase + kc*32 + quad*8);
      oacc = __builtin_amdgcn_mfma_f32_16x16x32_bf16(pa, vf, oacc, 0,0,0);
    }
    if (nb2 == 0){
      zp += __shfl_xor(zp, 16, 64);
      zp += __shfl_xor(zp, 32, 64);
      if (lane < 16) atomicAdd(&zsh[l16], zp);
    }
    #pragma unroll
    for (int r=0;r<4;r++)
      atomicAdd(&osh[(quad*4+r)*64 + nb2*16 + l16], oacc[r]);
    __syncthreads();

    // ---- epilogue: o/z gathered to (B, t, E) layout for out-proj
    {
      int r = tid >> 6, d = tid & 63;
      float val = osh[tid] / zsh[r];
      og[((size_t)(b*S_LEN + sq0 + r))*E_DIM + h*DH + d] = (bf16_t)val;
    }

    // ---- pass 3: accumulate head-mean attention weights in registers
    // thread (wave, lane) owns row wave, cols {g*256 + lane*4 .. +3}, g=0..7
    {
      const float inv3 = invr_sh[wave], m3 = msh[wave];
      const float sc = 0.125f / zsh[wave];
      const f32x4* ur3 = (const f32x4*)u_s + (size_t)wave*512;
      const int sw3 = wave & 7;
      #pragma unroll
      for (int g=0; g<8; g++){
        f32x4 u = ur3[(g*64 + lane) ^ sw3];
        awacc[g*4+0] = fmaf(__expf(u[0]*inv3 - m3), sc, awacc[g*4+0]);
        awacc[g*4+1] = fmaf(__expf(u[1]*inv3 - m3), sc, awacc[g*4+1]);
        awacc[g*4+2] = fmaf(__expf(u[2]*inv3 - m3), sc, awacc[g*4+2]);
        awacc[g*4+3] = fmaf(__expf(u[3]*inv3 - m3), sc, awacc[g*4+3]);
      }
    }
    __syncthreads();   // protect u_s / osh / zsh / invr / msh for next head
  }

  // ---- single coalesced aw write: 8 x f32x4 NT stores per thread
  float* awrow = aw + ((size_t)(b*S_LEN) + sq0 + wave)*S_LEN + (size_t)lane*4;
  #pragma unroll
  for (int g=0; g<8; g++){
    f32x4 v = (f32x4){ awacc[g*4+0], awacc[g*4+1], awacc[g*4+2], awacc[g*4+3] };
    __builtin_nontemporal_store(v, (f32x4*)(awrow + g*256));
  }
}

// ---------------- launch ----------------
extern "C" void kernel_launch(void* const* d_in, const int* in_sizes, int n_in,
                              void* d_out, int out_size, void* d_ws, size_t ws_size,
                              hipStream_t stream)
{
  const float* query     = (const float*)d_in[0];
  const float* gate      = (const float*)d_in[1];
  const float* in_proj_w = (const float*)d_in[2];
  const float* in_proj_b = (const float*)d_in[3];
  const float* out_w     = (const float*)d_in[4];
  const float* out_b     = (const float*)d_in[5];
  const float* ln1_w     = (const float*)d_in[6];
  const float* ln1_b     = (const float*)d_in[7];
  const float* ln2_w     = (const float*)d_in[8];
  const float* ln2_b     = (const float*)d_in[9];
  const float* w1        = (const float*)d_in[10];
  const float* b1        = (const float*)d_in[11];
  const float* w2        = (const float*)d_in[12];
  const float* b2        = (const float*)d_in[13];

  char* ws = (char*)d_ws;
  bf16_t* nqh   = (bf16_t*)(ws);                    // 4 MB
  bf16_t* nql   = (bf16_t*)(ws + ((size_t)4<<20));  // 4 MB
  bf16_t* qh    = (bf16_t*)(ws + ((size_t)8<<20));  // 4 MB
  bf16_t* ql    = (bf16_t*)(ws + ((size_t)12<<20)); // 4 MB
  bf16_t* kh    = (bf16_t*)(ws + ((size_t)16<<20)); // 4 MB
  bf16_t* kl    = (bf16_t*)(ws + ((size_t)20<<20)); // 4 MB
  bf16_t* vtmp  = (bf16_t*)(ws + ((size_t)24<<20)); // 4 MB
  bf16_t* vt    = (bf16_t*)(ws + ((size_t)28<<20)); // 4 MB
  bf16_t* og    = (bf16_t*)(ws + ((size_t)32<<20)); // 4 MB
  bf16_t* hmid  = (bf16_t*)(ws + ((size_t)36<<20)); // 4 MB
  bf16_t* h1    = (bf16_t*)(ws + ((size_t)40<<20)); // 16 MB
  bf16_t* wqh   = (bf16_t*)(ws + ((size_t)56<<20)); // 1.5 MB
  bf16_t* wql   = (bf16_t*)(ws + ((size_t)58<<20)); // 1.5 MB
  bf16_t* woutb = (bf16_t*)(ws + ((size_t)60<<20)); // 0.5 MB
  bf16_t* w1b   = (bf16_t*)(ws + ((size_t)61<<20)); // 2 MB
  bf16_t* w2b   = (bf16_t*)(ws + ((size_t)63<<20)); // 2 MB

  float* xout = (float*)d_out;                       // (B,S,E) fp32
  float* aw   = xout + (size_t)2*S_LEN*E_DIM;        // (B,S,S) fp32

  cvt_split_kernel<<<768, 256, 0, stream>>>(in_proj_w, wqh, wql, 786432);
  cvt_kernel<<<256, 256, 0, stream>>>(out_w, woutb, 262144);
  cvt_kernel<<<1024,256, 0, stream>>>(w1,    w1b,   1048576);
  cvt_kernel<<<1024,256, 0, stream>>>(w2,    w2b,   1048576);

  // ln1(query) -> split nq
  ln_split_kernel<<<1024, 256, 0, stream>>>(query, ln1_w, ln1_b, nqh, nql);

  // qkv split GEMM: q,k as hi/lo pairs; v plain flat
  gemm_qkv_split<<<768, 256, 0, stream>>>(nqh, nql, wqh, wql, in_proj_b,
                                          qh, ql, kh, kl, vtmp);

  // v -> vt[i][d][t] (raw-reshape pseudo-head transpose)
  vtrans_kernel<<<128, 256, 0, stream>>>(vtmp, vt);

  // fused gated-renorm softmax attention: 256 blocks, 8 heads/block, no atomics
  attn_kernel<<<256, 1024, 0, stream>>>(qh, ql, kh, kl, vt, gate, og, aw);

  // x = query + og @ out_w^T + out_b   (fp32 -> d_out)
  gemm_kernel<64,1><<<256, 256, 0, stream>>>(og, woutb, out_b,
      4096, 512, 512, (void*)xout, query);

  // hmid = ln2(x)
  ln_kernel<<<1024, 256, 0, stream>>>(xout, ln2_w, ln2_b, hmid);

  // h1 = gelu(hmid @ w1^T + b1)
  gemm_kernel<128,2><<<512, 256, 0, stream>>>(hmid, w1b, b1,
      4096, 2048, 512, (void*)h1, nullptr);

  // x += h1 @ w2^T + b2
  gemm_kernel<64,3><<<256, 256, 0, stream>>>(h1, w2b, b2,
      4096, 512, 2048, (void*)xout, nullptr);
}

// Round 2
// 815.559 us; speedup vs baseline: 1.0531x; 1.0531x over previous
//
#include <hip/hip_runtime.h>
#include <cstdint>
#include <cstddef>

typedef __bf16 bf16_t;
typedef __bf16 bf16x8 __attribute__((ext_vector_type(8)));
typedef float  f32x4  __attribute__((ext_vector_type(4)));

#define S_LEN   2048
#define E_DIM   512
#define H_NUM   8
#define DH      64
#define MLP_DIM 2048

static __device__ __forceinline__ unsigned short f2bfu(float f){
  bf16_t h = (bf16_t)f;
  return __builtin_bit_cast(unsigned short, h);
}

static __device__ __forceinline__ float gelu_f(float v){
  return 0.5f*v*(1.0f + erff(v*0.70710678118654752f));
}

// ---------------- fp32 -> bf16 convert (plain) ----------------
__global__ __launch_bounds__(256) void cvt_kernel(const float* __restrict__ s,
                                                  bf16_t* __restrict__ d, int n){
  int i = (blockIdx.x*256 + threadIdx.x)*4;
  if (i < n){
    float4 v = *(const float4*)(s + i);
    ushort4 pk;
    pk.x = f2bfu(v.x); pk.y = f2bfu(v.y); pk.z = f2bfu(v.z); pk.w = f2bfu(v.w);
    *(ushort4*)((unsigned short*)d + i) = pk;
  }
}

// ---------------- fp32 -> split (hi+lo) bf16 convert ----------------
__global__ __launch_bounds__(256) void cvt_split_kernel(const float* __restrict__ s,
                                                        bf16_t* __restrict__ dh,
                                                        bf16_t* __restrict__ dl, int n){
  int i = (blockIdx.x*256 + threadIdx.x)*4;
  if (i < n){
    float4 v = *(const float4*)(s + i);
    float xs[4] = {v.x, v.y, v.z, v.w};
    ushort4 ph, pl;
    unsigned short* hp = (unsigned short*)&ph;
    unsigned short* lp = (unsigned short*)&pl;
    #pragma unroll
    for (int j=0;j<4;j++){
      bf16_t hi = (bf16_t)xs[j];
      bf16_t lo = (bf16_t)(xs[j] - (float)hi);
      hp[j] = __builtin_bit_cast(unsigned short, hi);
      lp[j] = __builtin_bit_cast(unsigned short, lo);
    }
    *(ushort4*)((unsigned short*)dh + i) = ph;
    *(ushort4*)((unsigned short*)dl + i) = pl;
  }
}

// ---------------- LayerNorm (plain bf16 out): one wave per row ----------------
__global__ __launch_bounds__(256) void ln_kernel(const float* __restrict__ x,
                                                 const float* __restrict__ w,
                                                 const float* __restrict__ bb,
                                                 bf16_t* __restrict__ out){
  const int row  = blockIdx.x*4 + (threadIdx.x>>6);
  const int lane = threadIdx.x & 63;
  const float* xr = x + (size_t)row*E_DIM + lane*8;
  float4 v0 = *(const float4*)xr;
  float4 v1 = *(const float4*)(xr + 4);
  float xs[8] = {v0.x, v0.y, v0.z, v0.w, v1.x, v1.y, v1.z, v1.w};
  float s = 0.f, s2 = 0.f;
  #pragma unroll
  for (int j=0;j<8;j++){ s += xs[j]; s2 += xs[j]*xs[j]; }
  #pragma unroll
  for (int off=1; off<64; off<<=1){
    s  += __shfl_xor(s,  off, 64);
    s2 += __shfl_xor(s2, off, 64);
  }
  float mean = s*(1.f/512.f);
  float var  = s2*(1.f/512.f) - mean*mean;
  float rstd = rsqrtf(fmaxf(var, 0.f) + 1e-5f);
  const float* wp = w  + lane*8;
  const float* bp = bb + lane*8;
  bf16x8 ov;
  #pragma unroll
  for (int j=0;j<8;j++)
    ov[j] = (bf16_t)((xs[j]-mean)*rstd*wp[j] + bp[j]);
  *(bf16x8*)(out + (size_t)row*E_DIM + lane*8) = ov;
}

// ---------------- LayerNorm with split hi/lo bf16 output ----------------
__global__ __launch_bounds__(256) void ln_split_kernel(const float* __restrict__ x,
                                                       const float* __restrict__ w,
                                                       const float* __restrict__ bb,
                                                       bf16_t* __restrict__ oh,
                                                       bf16_t* __restrict__ ol){
  const int row  = blockIdx.x*4 + (threadIdx.x>>6);
  const int lane = threadIdx.x & 63;
  const float* xr = x + (size_t)row*E_DIM + lane*8;
  float4 v0 = *(const float4*)xr;
  float4 v1 = *(const float4*)(xr + 4);
  float xs[8] = {v0.x, v0.y, v0.z, v0.w, v1.x, v1.y, v1.z, v1.w};
  float s = 0.f, s2 = 0.f;
  #pragma unroll
  for (int j=0;j<8;j++){ s += xs[j]; s2 += xs[j]*xs[j]; }
  #pragma unroll
  for (int off=1; off<64; off<<=1){
    s  += __shfl_xor(s,  off, 64);
    s2 += __shfl_xor(s2, off, 64);
  }
  float mean = s*(1.f/512.f);
  float var  = s2*(1.f/512.f) - mean*mean;
  float rstd = rsqrtf(fmaxf(var, 0.f) + 1e-5f);
  const float* wp = w  + lane*8;
  const float* bp = bb + lane*8;
  bf16x8 vh, vl;
  #pragma unroll
  for (int j=0;j<8;j++){
    float v = (xs[j]-mean)*rstd*wp[j] + bp[j];
    bf16_t hi = (bf16_t)v;
    vh[j] = hi;
    vl[j] = (bf16_t)(v - (float)hi);
  }
  size_t o = (size_t)row*E_DIM + lane*8;
  *(bf16x8*)(oh + o) = vh;
  *(bf16x8*)(ol + o) = vl;
}

// ---------------- split-precision QKV GEMM ----------------
__global__ __launch_bounds__(256) void gemm_qkv_split(
    const bf16_t* __restrict__ Ah, const bf16_t* __restrict__ Al,
    const bf16_t* __restrict__ Bh, const bf16_t* __restrict__ Bl,
    const float* __restrict__ bias,
    bf16_t* __restrict__ qh, bf16_t* __restrict__ ql,
    bf16_t* __restrict__ kh, bf16_t* __restrict__ kl,
    bf16_t* __restrict__ vtmp)
{
  constexpr int TM = 128, TN = 64, BK = 64, MI = 4, NI = 2;
  const int K = 512;

  __shared__ bf16_t Ahs[TM*BK], Als[TM*BK];
  __shared__ bf16_t Bhs[TN*BK], Bls[TN*BK];

  const int tid  = threadIdx.x;
  const int wave = tid>>6, lane = tid&63, quad = lane>>4, l16 = lane&15;
  const int wm = wave>>1, wn = wave&1;

  const int nblk = 1536/TN;
  const int bm = blockIdx.x / nblk;
  const int bn = blockIdx.x % nblk;
  const int m0 = bm*TM, n0 = bn*TN;

  f32x4 acc[MI][NI];
  #pragma unroll
  for (int i=0;i<MI;i++)
    #pragma unroll
    for (int j=0;j<NI;j++)
      acc[i][j] = (f32x4){0.f,0.f,0.f,0.f};

  for (int k0 = 0; k0 < K; k0 += BK){
    bf16x8 avh[4], avl[4], bvh[2], bvl[2];
    #pragma unroll
    for (int i=0;i<4;i++){
      int ga = tid + i*256;
      int row = ga>>3, c8 = (ga&7) ^ (row&7);
      size_t off = (size_t)(m0+row)*K + k0 + c8*8;
      avh[i] = *(const bf16x8*)(Ah + off);
      avl[i] = *(const bf16x8*)(Al + off);
    }
    #pragma unroll
    for (int i=0;i<2;i++){
      int gb = tid + i*256;
      int row = gb>>3, c8 = (gb&7) ^ (row&7);
      size_t off = (size_t)(n0+row)*K + k0 + c8*8;
      bvh[i] = *(const bf16x8*)(Bh + off);
      bvl[i] = *(const bf16x8*)(Bl + off);
    }
    __syncthreads();
    #pragma unroll
    for (int i=0;i<4;i++){
      *(bf16x8*)(Ahs + (size_t)(tid + i*256)*8) = avh[i];
      *(bf16x8*)(Als + (size_t)(tid + i*256)*8) = avl[i];
    }
    #pragma unroll
    for (int i=0;i<2;i++){
      *(bf16x8*)(Bhs + (size_t)(tid + i*256)*8) = bvh[i];
      *(bf16x8*)(Bls + (size_t)(tid + i*256)*8) = bvl[i];
    }
    __syncthreads();
    #pragma unroll
    for (int ks=0;ks<2;ks++){
      bf16x8 afh[MI], afl[MI], bfh[NI], bfl[NI];
      #pragma unroll
      for (int mi=0;mi<MI;mi++){
        int rm = wm*64 + mi*16 + l16;
        size_t sl = (size_t)(rm*8 + ((ks*4+quad) ^ (rm&7)))*8;
        afh[mi] = *(const bf16x8*)(Ahs + sl);
        afl[mi] = *(const bf16x8*)(Als + sl);
      }
      #pragma unroll
      for (int ni=0;ni<NI;ni++){
        int rn = wn*32 + ni*16 + l16;
        size_t sl = (size_t)(rn*8 + ((ks*4+quad) ^ (rn&7)))*8;
        bfh[ni] = *(const bf16x8*)(Bhs + sl);
        bfl[ni] = *(const bf16x8*)(Bls + sl);
      }
      #pragma unroll
      for (int mi=0;mi<MI;mi++)
        #pragma unroll
        for (int ni=0;ni<NI;ni++){
          acc[mi][ni] = __builtin_amdgcn_mfma_f32_16x16x32_bf16(afh[mi], bfh[ni], acc[mi][ni], 0,0,0);
          acc[mi][ni] = __builtin_amdgcn_mfma_f32_16x16x32_bf16(afl[mi], bfh[ni], acc[mi][ni], 0,0,0);
          acc[mi][ni] = __builtin_amdgcn_mfma_f32_16x16x32_bf16(afh[mi], bfl[ni], acc[mi][ni], 0,0,0);
        }
    }
  }

  #pragma unroll
  for (int mi=0;mi<MI;mi++){
    const int grow0 = m0 + wm*64 + mi*16 + quad*4;
    #pragma unroll
    for (int ni=0;ni<NI;ni++){
      const int gcol = n0 + wn*32 + ni*16 + l16;
      const float bvx = bias[gcol];
      if (gcol < 512){
        #pragma unroll
        for (int r=0;r<4;r++){
          float v = acc[mi][ni][r] + bvx;
          size_t idx = (size_t)(grow0+r)*E_DIM + gcol;
          bf16_t hi = (bf16_t)v;
          qh[idx] = hi;
          ql[idx] = (bf16_t)(v - (float)hi);
        }
      } else if (gcol < 1024){
        const int cc = gcol - 512;
        #pragma unroll
        for (int r=0;r<4;r++){
          float v = acc[mi][ni][r] + bvx;
          size_t idx = (size_t)(grow0+r)*E_DIM + cc;
          bf16_t hi = (bf16_t)v;
          kh[idx] = hi;
          kl[idx] = (bf16_t)(v - (float)hi);
        }
      } else {
        const int cc = gcol - 1024;
        #pragma unroll
        for (int r=0;r<4;r++)
          vtmp[(size_t)(grow0+r)*E_DIM + cc] = (bf16_t)(acc[mi][ni][r] + bvx);
      }
    }
  }
}

// ---------------- V transpose: (B,S,E) flat -> vt[i][d][t] ----------------
__global__ __launch_bounds__(256) void vtrans_kernel(const bf16_t* __restrict__ v,
                                                     bf16_t* __restrict__ vt){
  __shared__ bf16_t tile[32*516];
  const int ic = blockIdx.x >> 3;
  const int rg = blockIdx.x & 7;
  const int tid = threadIdx.x;
  const size_t src = ((size_t)ic*256 + rg*32)*E_DIM;
  #pragma unroll
  for (int j=0;j<8;j++){
    int idx = j*2048 + tid*8;
    int row = idx >> 9, col = idx & 511;
    *(bf16x8*)(tile + row*516 + col) = *(const bf16x8*)(v + src + idx);
  }
  __syncthreads();
  #pragma unroll
  for (int j=0;j<8;j++){
    int idx = j*2048 + tid*8;
    int d = idx >> 8;
    int toff = idx & 255;
    int row = toff >> 3;
    bf16x8 o;
    #pragma unroll
    for (int jj=0;jj<8;jj++)
      o[jj] = tile[row*516 + jj*64 + d];
    *(bf16x8*)(vt + ((size_t)ic*64 + d)*S_LEN + rg*256 + toff) = o;
  }
}

// ---------------- plain bf16 GEMM ----------------
template<int TN, int MODE>
__global__ __launch_bounds__(256) void gemm_kernel(
    const bf16_t* __restrict__ A, const bf16_t* __restrict__ Bw,
    const float* __restrict__ bias, int M, int N, int K,
    void* out0, const float* __restrict__ resid)
{
  constexpr int TM = 128;
  constexpr int BK = 64;
  constexpr int MI = 4;
  constexpr int NI = TN/32;
  constexpr int GB = TN/32;

  __shared__ bf16_t As[TM*BK];
  __shared__ bf16_t Bs[TN*BK];

  const int tid  = threadIdx.x;
  const int wave = tid>>6, lane = tid&63, quad = lane>>4, l16 = lane&15;
  const int wm = wave>>1, wn = wave&1;

  const int nblk = N / TN;
  const int bm = blockIdx.x / nblk;
  const int bn = blockIdx.x % nblk;
  const int m0 = bm*TM, n0 = bn*TN;

  f32x4 acc[MI][NI];
  #pragma unroll
  for (int i=0;i<MI;i++)
    #pragma unroll
    for (int j=0;j<NI;j++)
      acc[i][j] = (f32x4){0.f,0.f,0.f,0.f};

  for (int k0 = 0; k0 < K; k0 += BK){
    bf16x8 av[4];
    #pragma unroll
    for (int i=0;i<4;i++){
      int ga = tid + i*256;
      int row = ga>>3, c8 = (ga&7) ^ (row&7);
      av[i] = *(const bf16x8*)(A + (size_t)(m0+row)*K + k0 + c8*8);
    }
    bf16x8 bv[GB];
    #pragma unroll
    for (int i=0;i<GB;i++){
      int gb = tid + i*256;
      int row = gb>>3, c8 = (gb&7) ^ (row&7);
      bv[i] = *(const bf16x8*)(Bw + (size_t)(n0+row)*K + k0 + c8*8);
    }
    __syncthreads();
    #pragma unroll
    for (int i=0;i<4;i++)  *(bf16x8*)(As + (size_t)(tid + i*256)*8) = av[i];
    #pragma unroll
    for (int i=0;i<GB;i++) *(bf16x8*)(Bs + (size_t)(tid + i*256)*8) = bv[i];
    __syncthreads();
    #pragma unroll
    for (int ks=0;ks<2;ks++){
      bf16x8 af[MI], bfr[NI];
      #pragma unroll
      for (int mi=0;mi<MI;mi++){
        int rm = wm*64 + mi*16 + l16;
        af[mi] = *(const bf16x8*)(As + (size_t)(rm*8 + ((ks*4+quad) ^ (rm&7)))*8);
      }
      #pragma unroll
      for (int ni=0;ni<NI;ni++){
        int rn = wn*(TN/2) + ni*16 + l16;
        bfr[ni] = *(const bf16x8*)(Bs + (size_t)(rn*8 + ((ks*4+quad) ^ (rn&7)))*8);
      }
      #pragma unroll
      for (int mi=0;mi<MI;mi++)
        #pragma unroll
        for (int ni=0;ni<NI;ni++)
          acc[mi][ni] = __builtin_amdgcn_mfma_f32_16x16x32_bf16(af[mi], bfr[ni], acc[mi][ni], 0,0,0);
    }
  }

  #pragma unroll
  for (int mi=0;mi<MI;mi++){
    const int grow0 = m0 + wm*64 + mi*16 + quad*4;
    #pragma unroll
    for (int ni=0;ni<NI;ni++){
      const int gcol = n0 + wn*(TN/2) + ni*16 + l16;
      const float bvx = bias[gcol];
      if constexpr (MODE==1){
        float* xo = (float*)out0;
        #pragma unroll
        for (int r=0;r<4;r++){
          size_t idx = (size_t)(grow0+r)*E_DIM + gcol;
          xo[idx] = resid[idx] + acc[mi][ni][r] + bvx;
        }
      } else if constexpr (MODE==2){
        bf16_t* hp = (bf16_t*)out0;
        #pragma unroll
        for (int r=0;r<4;r++)
          hp[(size_t)(grow0+r)*MLP_DIM + gcol] = (bf16_t)gelu_f(acc[mi][ni][r] + bvx);
      } else {
        float* xo = (float*)out0;
        #pragma unroll
        for (int r=0;r<4;r++){
          size_t idx = (size_t)(grow0+r)*E_DIM + gcol;
          xo[idx] = xo[idx] + acc[mi][ni][r] + bvx;
        }
      }
    }
  }
}

// ---------------- fused attention: one block = (b, 16 q-rows), loops 8 heads ----------------
// __launch_bounds__(1024, 4): LDS (131 KB) caps us at 1 block/CU = 4 waves/EU
// anyway, so claim the full 128-VGPR budget that entitles -> no scratch spills
// (round-1 regression: compiler capped at 64 VGPRs, spilled awacc/gpre -> +500 MB
// of scratch traffic). Gate is loaded inline in pass 1.5 (coalesced f32x4 NT),
// NOT held across phases.
__global__ __launch_bounds__(1024, 4) void attn_kernel(
    const bf16_t* __restrict__ qhb, const bf16_t* __restrict__ qlb,
    const bf16_t* __restrict__ khb, const bf16_t* __restrict__ klb,
    const bf16_t* __restrict__ vt,  const float* __restrict__ gate,
    bf16_t* __restrict__ og, float* __restrict__ aw)
{
  __shared__ __align__(16) float u_s[16*2048];   // 131072 B, float4-XOR swizzled
  __shared__ float osh[16*64];
  __shared__ float zsh[16];
  __shared__ float invr_sh[16];
  __shared__ float msh[16];

  const int b   = blockIdx.x >> 7;
  const int sqt = blockIdx.x & 127;
  const int sq0 = sqt*16;

  const int tid = threadIdx.x;
  const int wave = tid>>6, lane = tid&63, quad = lane>>4, l16 = lane&15;

  float awacc[32];
  #pragma unroll
  for (int j=0;j<32;j++) awacc[j] = 0.f;

  for (int h = 0; h < H_NUM; h++){
    const int bh = b*H_NUM + h;

    osh[tid] = 0.f;
    if (tid < 16) zsh[tid] = 0.f;

    bf16x8 qah0, qah1, qal0, qal1;
    {
      const size_t qoff = ((size_t)bh*S_LEN + sq0 + l16)*DH + quad*8;
      qah0 = *(const bf16x8*)(qhb + qoff);
      qah1 = *(const bf16x8*)(qhb + qoff + 32);
      qal0 = *(const bf16x8*)(qlb + qoff);
      qal1 = *(const bf16x8*)(qlb + qoff + 32);
    }

    // ---- pass 1: raw scores s = q.k^T -> swizzled LDS (no gate, no reductions)
    for (int cb = wave; cb < 32; cb += 16){
      #pragma unroll
      for (int nb=0; nb<4; nb++){
        const int col0 = cb*64 + nb*16;
        const size_t koff = ((size_t)bh*S_LEN + col0 + l16)*DH + quad*8;
        bf16x8 khf0 = *(const bf16x8*)(khb + koff);
        bf16x8 khf1 = *(const bf16x8*)(khb + koff + 32);
        bf16x8 klf0 = *(const bf16x8*)(klb + koff);
        bf16x8 klf1 = *(const bf16x8*)(klb + koff + 32);
        f32x4 acc = (f32x4){0.f,0.f,0.f,0.f};
        acc = __builtin_amdgcn_mfma_f32_16x16x32_bf16(qah0, khf0, acc, 0,0,0);
        acc = __builtin_amdgcn_mfma_f32_16x16x32_bf16(qah1, khf1, acc, 0,0,0);
        acc = __builtin_amdgcn_mfma_f32_16x16x32_bf16(qal0, khf0, acc, 0,0,0);
        acc = __builtin_amdgcn_mfma_f32_16x16x32_bf16(qal1, khf1, acc, 0,0,0);
        acc = __builtin_amdgcn_mfma_f32_16x16x32_bf16(qah0, klf0, acc, 0,0,0);
        acc = __builtin_amdgcn_mfma_f32_16x16x32_bf16(qah1, klf1, acc, 0,0,0);
        const int c = col0 + l16;
        #pragma unroll
        for (int r=0;r<4;r++){
          const int row = quad*4 + r;
          u_s[row*2048 + (c ^ ((row&7)<<2))] = acc[r];
        }
      }
    }
    __syncthreads();

    // ---- pass 1.5: u = s*gate (gate loaded inline); fp64 row sum + max/min, 1 wave = 1 row
    {
      f32x4* ub = (f32x4*)u_s + (size_t)wave*512;
      const int sw = wave & 7;
      const float* gp = gate + ((size_t)bh*S_LEN + sq0 + wave)*S_LEN + (size_t)lane*4;
      double s = 0.0;
      float mx = -__builtin_inff(), mn = __builtin_inff();
      #pragma unroll
      for (int it=0; it<8; it++){
        f32x4 g = __builtin_nontemporal_load((const f32x4*)(gp + it*256));
        const int c4 = (it*64 + lane) ^ sw;
        f32x4 u = ub[c4];
        u = u * g;
        ub[c4] = u;
        s += ((double)u[0] + (double)u[1]) + ((double)u[2] + (double)u[3]);
        mx = fmaxf(mx, fmaxf(fmaxf(u[0],u[1]), fmaxf(u[2],u[3])));
        mn = fminf(mn, fminf(fminf(u[0],u[1]), fminf(u[2],u[3])));
      }
      #pragma unroll
      for (int off=1; off<64; off<<=1){
        s  += __shfl_xor(s, off, 64);
        mx = fmaxf(mx, __shfl_xor(mx, off, 64));
        mn = fminf(mn, __shfl_xor(mn, off, 64));
      }
      if (lane == 0){
        double rsum = s + 1e-12;
        float inv = (float)(1.0/rsum);
        invr_sh[wave] = inv;
        msh[wave] = (rsum > 0.0 ? mx : mn) * inv;   // exact max of u*inv -> max e == 1
      }
    }
    __syncthreads();

    // ---- pass 2: e = exp(u*inv - m); z; o = e @ V  (16 waves: nb2 x k-quarter)
    const float inv_r = invr_sh[l16];
    const float m_v   = msh[l16];
    const int nb2 = wave & 3, kh2 = wave >> 2;
    f32x4 oacc = (f32x4){0.f,0.f,0.f,0.f};
    float zp = 0.f;
    const bf16_t* vbase = vt + ((size_t)bh*DH + nb2*16 + l16)*S_LEN;
    const f32x4* ur4 = (const f32x4*)u_s + (size_t)l16*512;
    const int swr = l16 & 7;
    for (int kc = kh2*16; kc < kh2*16 + 16; kc++){
      const int c4a = kc*8 + quad*2;
      f32x4 u0 = ur4[c4a ^ swr];
      f32x4 u1 = ur4[(c4a+1) ^ swr];
      float e0 = __expf(u0[0]*inv_r - m_v);
      float e1 = __expf(u0[1]*inv_r - m_v);
      float e2 = __expf(u0[2]*inv_r - m_v);
      float e3 = __expf(u0[3]*inv_r - m_v);
      float e4 = __expf(u1[0]*inv_r - m_v);
      float e5 = __expf(u1[1]*inv_r - m_v);
      float e6 = __expf(u1[2]*inv_r - m_v);
      float e7 = __expf(u1[3]*inv_r - m_v);
      if (nb2 == 0) zp += ((e0+e1)+(e2+e3)) + ((e4+e5)+(e6+e7));
      bf16x8 pa;
      pa[0]=(bf16_t)e0; pa[1]=(bf16_t)e1; pa[2]=(bf16_t)e2; pa[3]=(bf16_t)e3;
      pa[4]=(bf16_t)e4; pa[5]=(bf16_t)e5; pa[6]=(bf16_t)e6; pa[7]=(bf16_t)e7;
      bf16x8 vf = *(const bf16x8*)(vbase + kc*32 + quad*8);
      oacc = __builtin_amdgcn_mfma_f32_16x16x32_bf16(pa, vf, oacc, 0,0,0);
    }
    if (nb2 == 0){
      zp += __shfl_xor(zp, 16, 64);
      zp += __shfl_xor(zp, 32, 64);
      if (lane < 16) atomicAdd(&zsh[l16], zp);
    }
    #pragma unroll
    for (int r=0;r<4;r++)
      atomicAdd(&osh[(quad*4+r)*64 + nb2*16 + l16], oacc[r]);
    __syncthreads();

    // ---- epilogue: o/z gathered to (B, t, E) layout for out-proj
    {
      int r = tid >> 6, d = tid & 63;
      float val = osh[tid] / zsh[r];
      og[((size_t)(b*S_LEN + sq0 + r))*E_DIM + h*DH + d] = (bf16_t)val;
    }

    // ---- pass 3: accumulate head-mean attention weights in registers
    // thread (wave, lane) owns row wave, cols {g*256 + lane*4 .. +3}, g=0..7
    {
      const float inv3 = invr_sh[wave], m3 = msh[wave];
      const float sc = 0.125f / zsh[wave];
      const f32x4* ur3 = (const f32x4*)u_s + (size_t)wave*512;
      const int sw3 = wave & 7;
      #pragma unroll
      for (int g=0; g<8; g++){
        f32x4 u = ur3[(g*64 + lane) ^ sw3];
        awacc[g*4+0] = fmaf(__expf(u[0]*inv3 - m3), sc, awacc[g*4+0]);
        awacc[g*4+1] = fmaf(__expf(u[1]*inv3 - m3), sc, awacc[g*4+1]);
        awacc[g*4+2] = fmaf(__expf(u[2]*inv3 - m3), sc, awacc[g*4+2]);
        awacc[g*4+3] = fmaf(__expf(u[3]*inv3 - m3), sc, awacc[g*4+3]);
      }
    }
    __syncthreads();   // protect u_s / osh / zsh / invr / msh for next head
  }

  // ---- single coalesced aw write: 8 x f32x4 NT stores per thread
  float* awrow = aw + ((size_t)(b*S_LEN) + sq0 + wave)*S_LEN + (size_t)lane*4;
  #pragma unroll
  for (int g=0; g<8; g++){
    f32x4 v = (f32x4){ awacc[g*4+0], awacc[g*4+1], awacc[g*4+2], awacc[g*4+3] };
    __builtin_nontemporal_store(v, (f32x4*)(awrow + g*256));
  }
}

// ---------------- launch ----------------
extern "C" void kernel_launch(void* const* d_in, const int* in_sizes, int n_in,
                              void* d_out, int out_size, void* d_ws, size_t ws_size,
                              hipStream_t stream)
{
  const float* query     = (const float*)d_in[0];
  const float* gate      = (const float*)d_in[1];
  const float* in_proj_w = (const float*)d_in[2];
  const float* in_proj_b = (const float*)d_in[3];
  const float* out_w     = (const float*)d_in[4];
  const float* out_b     = (const float*)d_in[5];
  const float* ln1_w     = (const float*)d_in[6];
  const float* ln1_b     = (const float*)d_in[7];
  const float* ln2_w     = (const float*)d_in[8];
  const float* ln2_b     = (const float*)d_in[9];
  const float* w1        = (const float*)d_in[10];
  const float* b1        = (const float*)d_in[11];
  const float* w2        = (const float*)d_in[12];
  const float* b2        = (const float*)d_in[13];

  char* ws = (char*)d_ws;
  bf16_t* nqh   = (bf16_t*)(ws);                    // 4 MB
  bf16_t* nql   = (bf16_t*)(ws + ((size_t)4<<20));  // 4 MB
  bf16_t* qh    = (bf16_t*)(ws + ((size_t)8<<20));  // 4 MB
  bf16_t* ql    = (bf16_t*)(ws + ((size_t)12<<20)); // 4 MB
  bf16_t* kh    = (bf16_t*)(ws + ((size_t)16<<20)); // 4 MB
  bf16_t* kl    = (bf16_t*)(ws + ((size_t)20<<20)); // 4 MB
  bf16_t* vtmp  = (bf16_t*)(ws + ((size_t)24<<20)); // 4 MB
  bf16_t* vt    = (bf16_t*)(ws + ((size_t)28<<20)); // 4 MB
  bf16_t* og    = (bf16_t*)(ws + ((size_t)32<<20)); // 4 MB
  bf16_t* hmid  = (bf16_t*)(ws + ((size_t)36<<20)); // 4 MB
  bf16_t* h1    = (bf16_t*)(ws + ((size_t)40<<20)); // 16 MB
  bf16_t* wqh   = (bf16_t*)(ws + ((size_t)56<<20)); // 1.5 MB
  bf16_t* wql   = (bf16_t*)(ws + ((size_t)58<<20)); // 1.5 MB
  bf16_t* woutb = (bf16_t*)(ws + ((size_t)60<<20)); // 0.5 MB
  bf16_t* w1b   = (bf16_t*)(ws + ((size_t)61<<20)); // 2 MB
  bf16_t* w2b   = (bf16_t*)(ws + ((size_t)63<<20)); // 2 MB

  float* xout = (float*)d_out;                       // (B,S,E) fp32
  float* aw   = xout + (size_t)2*S_LEN*E_DIM;        // (B,S,S) fp32

  cvt_split_kernel<<<768, 256, 0, stream>>>(in_proj_w, wqh, wql, 786432);
  cvt_kernel<<<256, 256, 0, stream>>>(out_w, woutb, 262144);
  cvt_kernel<<<1024,256, 0, stream>>>(w1,    w1b,   1048576);
  cvt_kernel<<<1024,256, 0, stream>>>(w2,    w2b,   1048576);

  // ln1(query) -> split nq
  ln_split_kernel<<<1024, 256, 0, stream>>>(query, ln1_w, ln1_b, nqh, nql);

  // qkv split GEMM: q,k as hi/lo pairs; v plain flat
  gemm_qkv_split<<<768, 256, 0, stream>>>(nqh, nql, wqh, wql, in_proj_b,
                                          qh, ql, kh, kl, vtmp);

  // v -> vt[i][d][t] (raw-reshape pseudo-head transpose)
  vtrans_kernel<<<128, 256, 0, stream>>>(vtmp, vt);

  // fused gated-renorm softmax attention: 256 blocks, 8 heads/block, no atomics
  attn_kernel<<<256, 1024, 0, stream>>>(qh, ql, kh, kl, vt, gate, og, aw);

  // x = query + og @ out_w^T + out_b   (fp32 -> d_out)
  gemm_kernel<64,1><<<256, 256, 0, stream>>>(og, woutb, out_b,
      4096, 512, 512, (void*)xout, query);

  // hmid = ln2(x)
  ln_kernel<<<1024, 256, 0, stream>>>(xout, ln2_w, ln2_b, hmid);

  // h1 = gelu(hmid @ w1^T + b1)
  gemm_kernel<128,2><<<512, 256, 0, stream>>>(hmid, w1b, b1,
      4096, 2048, 512, (void*)h1, nullptr);

  // x += h1 @ w2^T + b2
  gemm_kernel<64,3><<<256, 256, 0, stream>>>(h1, w2b, b2,
      4096, 512, 2048, (void*)xout, nullptr);
}

// Round 3
// 705.769 us; speedup vs baseline: 1.2169x; 1.1556x over previous
//
#include <hip/hip_runtime.h>
#include <cstdint>
#include <cstddef>

typedef __bf16 bf16_t;
typedef __bf16 bf16x8 __attribute__((ext_vector_type(8)));
typedef float  f32x4  __attribute__((ext_vector_type(4)));

#define S_LEN   2048
#define E_DIM   512
#define H_NUM   8
#define DH      64
#define MLP_DIM 2048

static __device__ __forceinline__ unsigned short f2bfu(float f){
  bf16_t h = (bf16_t)f;
  return __builtin_bit_cast(unsigned short, h);
}

static __device__ __forceinline__ float gelu_f(float v){
  return 0.5f*v*(1.0f + erff(v*0.70710678118654752f));
}

// ---------------- fp32 -> bf16 convert (plain) ----------------
__global__ __launch_bounds__(256) void cvt_kernel(const float* __restrict__ s,
                                                  bf16_t* __restrict__ d, int n){
  int i = (blockIdx.x*256 + threadIdx.x)*4;
  if (i < n){
    float4 v = *(const float4*)(s + i);
    ushort4 pk;
    pk.x = f2bfu(v.x); pk.y = f2bfu(v.y); pk.z = f2bfu(v.z); pk.w = f2bfu(v.w);
    *(ushort4*)((unsigned short*)d + i) = pk;
  }
}

// ---------------- fp32 -> split (hi+lo) bf16 convert ----------------
__global__ __launch_bounds__(256) void cvt_split_kernel(const float* __restrict__ s,
                                                        bf16_t* __restrict__ dh,
                                                        bf16_t* __restrict__ dl, int n){
  int i = (blockIdx.x*256 + threadIdx.x)*4;
  if (i < n){
    float4 v = *(const float4*)(s + i);
    float xs[4] = {v.x, v.y, v.z, v.w};
    ushort4 ph, pl;
    unsigned short* hp = (unsigned short*)&ph;
    unsigned short* lp = (unsigned short*)&pl;
    #pragma unroll
    for (int j=0;j<4;j++){
      bf16_t hi = (bf16_t)xs[j];
      bf16_t lo = (bf16_t)(xs[j] - (float)hi);
      hp[j] = __builtin_bit_cast(unsigned short, hi);
      lp[j] = __builtin_bit_cast(unsigned short, lo);
    }
    *(ushort4*)((unsigned short*)dh + i) = ph;
    *(ushort4*)((unsigned short*)dl + i) = pl;
  }
}

// ---------------- LayerNorm (plain bf16 out): one wave per row ----------------
__global__ __launch_bounds__(256) void ln_kernel(const float* __restrict__ x,
                                                 const float* __restrict__ w,
                                                 const float* __restrict__ bb,
                                                 bf16_t* __restrict__ out){
  const int row  = blockIdx.x*4 + (threadIdx.x>>6);
  const int lane = threadIdx.x & 63;
  const float* xr = x + (size_t)row*E_DIM + lane*8;
  float4 v0 = *(const float4*)xr;
  float4 v1 = *(const float4*)(xr + 4);
  float xs[8] = {v0.x, v0.y, v0.z, v0.w, v1.x, v1.y, v1.z, v1.w};
  float s = 0.f, s2 = 0.f;
  #pragma unroll
  for (int j=0;j<8;j++){ s += xs[j]; s2 += xs[j]*xs[j]; }
  #pragma unroll
  for (int off=1; off<64; off<<=1){
    s  += __shfl_xor(s,  off, 64);
    s2 += __shfl_xor(s2, off, 64);
  }
  float mean = s*(1.f/512.f);
  float var  = s2*(1.f/512.f) - mean*mean;
  float rstd = rsqrtf(fmaxf(var, 0.f) + 1e-5f);
  const float* wp = w  + lane*8;
  const float* bp = bb + lane*8;
  bf16x8 ov;
  #pragma unroll
  for (int j=0;j<8;j++)
    ov[j] = (bf16_t)((xs[j]-mean)*rstd*wp[j] + bp[j]);
  *(bf16x8*)(out + (size_t)row*E_DIM + lane*8) = ov;
}

// ---------------- LayerNorm with split hi/lo bf16 output ----------------
__global__ __launch_bounds__(256) void ln_split_kernel(const float* __restrict__ x,
                                                       const float* __restrict__ w,
                                                       const float* __restrict__ bb,
                                                       bf16_t* __restrict__ oh,
                                                       bf16_t* __restrict__ ol){
  const int row  = blockIdx.x*4 + (threadIdx.x>>6);
  const int lane = threadIdx.x & 63;
  const float* xr = x + (size_t)row*E_DIM + lane*8;
  float4 v0 = *(const float4*)xr;
  float4 v1 = *(const float4*)(xr + 4);
  float xs[8] = {v0.x, v0.y, v0.z, v0.w, v1.x, v1.y, v1.z, v1.w};
  float s = 0.f, s2 = 0.f;
  #pragma unroll
  for (int j=0;j<8;j++){ s += xs[j]; s2 += xs[j]*xs[j]; }
  #pragma unroll
  for (int off=1; off<64; off<<=1){
    s  += __shfl_xor(s,  off, 64);
    s2 += __shfl_xor(s2, off, 64);
  }
  float mean = s*(1.f/512.f);
  float var  = s2*(1.f/512.f) - mean*mean;
  float rstd = rsqrtf(fmaxf(var, 0.f) + 1e-5f);
  const float* wp = w  + lane*8;
  const float* bp = bb + lane*8;
  bf16x8 vh, vl;
  #pragma unroll
  for (int j=0;j<8;j++){
    float v = (xs[j]-mean)*rstd*wp[j] + bp[j];
    bf16_t hi = (bf16_t)v;
    vh[j] = hi;
    vl[j] = (bf16_t)(v - (float)hi);
  }
  size_t o = (size_t)row*E_DIM + lane*8;
  *(bf16x8*)(oh + o) = vh;
  *(bf16x8*)(ol + o) = vl;
}

// ---------------- split-precision QKV GEMM ----------------
__global__ __launch_bounds__(256) void gemm_qkv_split(
    const bf16_t* __restrict__ Ah, const bf16_t* __restrict__ Al,
    const bf16_t* __restrict__ Bh, const bf16_t* __restrict__ Bl,
    const float* __restrict__ bias,
    bf16_t* __restrict__ qh, bf16_t* __restrict__ ql,
    bf16_t* __restrict__ kh, bf16_t* __restrict__ kl,
    bf16_t* __restrict__ vtmp)
{
  constexpr int TM = 128, TN = 64, BK = 64, MI = 4, NI = 2;
  const int K = 512;

  __shared__ bf16_t Ahs[TM*BK], Als[TM*BK];
  __shared__ bf16_t Bhs[TN*BK], Bls[TN*BK];

  const int tid  = threadIdx.x;
  const int wave = tid>>6, lane = tid&63, quad = lane>>4, l16 = lane&15;
  const int wm = wave>>1, wn = wave&1;

  const int nblk = 1536/TN;
  const int bm = blockIdx.x / nblk;
  const int bn = blockIdx.x % nblk;
  const int m0 = bm*TM, n0 = bn*TN;

  f32x4 acc[MI][NI];
  #pragma unroll
  for (int i=0;i<MI;i++)
    #pragma unroll
    for (int j=0;j<NI;j++)
      acc[i][j] = (f32x4){0.f,0.f,0.f,0.f};

  for (int k0 = 0; k0 < K; k0 += BK){
    bf16x8 avh[4], avl[4], bvh[2], bvl[2];
    #pragma unroll
    for (int i=0;i<4;i++){
      int ga = tid + i*256;
      int row = ga>>3, c8 = (ga&7) ^ (row&7);
      size_t off = (size_t)(m0+row)*K + k0 + c8*8;
      avh[i] = *(const bf16x8*)(Ah + off);
      avl[i] = *(const bf16x8*)(Al + off);
    }
    #pragma unroll
    for (int i=0;i<2;i++){
      int gb = tid + i*256;
      int row = gb>>3, c8 = (gb&7) ^ (row&7);
      size_t off = (size_t)(n0+row)*K + k0 + c8*8;
      bvh[i] = *(const bf16x8*)(Bh + off);
      bvl[i] = *(const bf16x8*)(Bl + off);
    }
    __syncthreads();
    #pragma unroll
    for (int i=0;i<4;i++){
      *(bf16x8*)(Ahs + (size_t)(tid + i*256)*8) = avh[i];
      *(bf16x8*)(Als + (size_t)(tid + i*256)*8) = avl[i];
    }
    #pragma unroll
    for (int i=0;i<2;i++){
      *(bf16x8*)(Bhs + (size_t)(tid + i*256)*8) = bvh[i];
      *(bf16x8*)(Bls + (size_t)(tid + i*256)*8) = bvl[i];
    }
    __syncthreads();
    #pragma unroll
    for (int ks=0;ks<2;ks++){
      bf16x8 afh[MI], afl[MI], bfh[NI], bfl[NI];
      #pragma unroll
      for (int mi=0;mi<MI;mi++){
        int rm = wm*64 + mi*16 + l16;
        size_t sl = (size_t)(rm*8 + ((ks*4+quad) ^ (rm&7)))*8;
        afh[mi] = *(const bf16x8*)(Ahs + sl);
        afl[mi] = *(const bf16x8*)(Als + sl);
      }
      #pragma unroll
      for (int ni=0;ni<NI;ni++){
        int rn = wn*32 + ni*16 + l16;
        size_t sl = (size_t)(rn*8 + ((ks*4+quad) ^ (rn&7)))*8;
        bfh[ni] = *(const bf16x8*)(Bhs + sl);
        bfl[ni] = *(const bf16x8*)(Bls + sl);
      }
      #pragma unroll
      for (int mi=0;mi<MI;mi++)
        #pragma unroll
        for (int ni=0;ni<NI;ni++){
          acc[mi][ni] = __builtin_amdgcn_mfma_f32_16x16x32_bf16(afh[mi], bfh[ni], acc[mi][ni], 0,0,0);
          acc[mi][ni] = __builtin_amdgcn_mfma_f32_16x16x32_bf16(afl[mi], bfh[ni], acc[mi][ni], 0,0,0);
          acc[mi][ni] = __builtin_amdgcn_mfma_f32_16x16x32_bf16(afh[mi], bfl[ni], acc[mi][ni], 0,0,0);
        }
    }
  }

  #pragma unroll
  for (int mi=0;mi<MI;mi++){
    const int grow0 = m0 + wm*64 + mi*16 + quad*4;
    #pragma unroll
    for (int ni=0;ni<NI;ni++){
      const int gcol = n0 + wn*32 + ni*16 + l16;
      const float bvx = bias[gcol];
      if (gcol < 512){
        #pragma unroll
        for (int r=0;r<4;r++){
          float v = acc[mi][ni][r] + bvx;
          size_t idx = (size_t)(grow0+r)*E_DIM + gcol;
          bf16_t hi = (bf16_t)v;
          qh[idx] = hi;
          ql[idx] = (bf16_t)(v - (float)hi);
        }
      } else if (gcol < 1024){
        const int cc = gcol - 512;
        #pragma unroll
        for (int r=0;r<4;r++){
          float v = acc[mi][ni][r] + bvx;
          size_t idx = (size_t)(grow0+r)*E_DIM + cc;
          bf16_t hi = (bf16_t)v;
          kh[idx] = hi;
          kl[idx] = (bf16_t)(v - (float)hi);
        }
      } else {
        const int cc = gcol - 1024;
        #pragma unroll
        for (int r=0;r<4;r++)
          vtmp[(size_t)(grow0+r)*E_DIM + cc] = (bf16_t)(acc[mi][ni][r] + bvx);
      }
    }
  }
}

// ---------------- V transpose: (B,S,E) flat -> vt[i][d][t] ----------------
__global__ __launch_bounds__(256) void vtrans_kernel(const bf16_t* __restrict__ v,
                                                     bf16_t* __restrict__ vt){
  __shared__ bf16_t tile[32*516];
  const int ic = blockIdx.x >> 3;
  const int rg = blockIdx.x & 7;
  const int tid = threadIdx.x;
  const size_t src = ((size_t)ic*256 + rg*32)*E_DIM;
  #pragma unroll
  for (int j=0;j<8;j++){
    int idx = j*2048 + tid*8;
    int row = idx >> 9, col = idx & 511;
    *(bf16x8*)(tile + row*516 + col) = *(const bf16x8*)(v + src + idx);
  }
  __syncthreads();
  #pragma unroll
  for (int j=0;j<8;j++){
    int idx = j*2048 + tid*8;
    int d = idx >> 8;
    int toff = idx & 255;
    int row = toff >> 3;
    bf16x8 o;
    #pragma unroll
    for (int jj=0;jj<8;jj++)
      o[jj] = tile[row*516 + jj*64 + d];
    *(bf16x8*)(vt + ((size_t)ic*64 + d)*S_LEN + rg*256 + toff) = o;
  }
}

// ---------------- plain bf16 GEMM ----------------
template<int TN, int MODE>
__global__ __launch_bounds__(256) void gemm_kernel(
    const bf16_t* __restrict__ A, const bf16_t* __restrict__ Bw,
    const float* __restrict__ bias, int M, int N, int K,
    void* out0, const float* __restrict__ resid)
{
  constexpr int TM = 128;
  constexpr int BK = 64;
  constexpr int MI = 4;
  constexpr int NI = TN/32;
  constexpr int GB = TN/32;

  __shared__ bf16_t As[TM*BK];
  __shared__ bf16_t Bs[TN*BK];

  const int tid  = threadIdx.x;
  const int wave = tid>>6, lane = tid&63, quad = lane>>4, l16 = lane&15;
  const int wm = wave>>1, wn = wave&1;

  const int nblk = N / TN;
  const int bm = blockIdx.x / nblk;
  const int bn = blockIdx.x % nblk;
  const int m0 = bm*TM, n0 = bn*TN;

  f32x4 acc[MI][NI];
  #pragma unroll
  for (int i=0;i<MI;i++)
    #pragma unroll
    for (int j=0;j<NI;j++)
      acc[i][j] = (f32x4){0.f,0.f,0.f,0.f};

  for (int k0 = 0; k0 < K; k0 += BK){
    bf16x8 av[4];
    #pragma unroll
    for (int i=0;i<4;i++){
      int ga = tid + i*256;
      int row = ga>>3, c8 = (ga&7) ^ (row&7);
      av[i] = *(const bf16x8*)(A + (size_t)(m0+row)*K + k0 + c8*8);
    }
    bf16x8 bv[GB];
    #pragma unroll
    for (int i=0;i<GB;i++){
      int gb = tid + i*256;
      int row = gb>>3, c8 = (gb&7) ^ (row&7);
      bv[i] = *(const bf16x8*)(Bw + (size_t)(n0+row)*K + k0 + c8*8);
    }
    __syncthreads();
    #pragma unroll
    for (int i=0;i<4;i++)  *(bf16x8*)(As + (size_t)(tid + i*256)*8) = av[i];
    #pragma unroll
    for (int i=0;i<GB;i++) *(bf16x8*)(Bs + (size_t)(tid + i*256)*8) = bv[i];
    __syncthreads();
    #pragma unroll
    for (int ks=0;ks<2;ks++){
      bf16x8 af[MI], bfr[NI];
      #pragma unroll
      for (int mi=0;mi<MI;mi++){
        int rm = wm*64 + mi*16 + l16;
        af[mi] = *(const bf16x8*)(As + (size_t)(rm*8 + ((ks*4+quad) ^ (rm&7)))*8);
      }
      #pragma unroll
      for (int ni=0;ni<NI;ni++){
        int rn = wn*(TN/2) + ni*16 + l16;
        bfr[ni] = *(const bf16x8*)(Bs + (size_t)(rn*8 + ((ks*4+quad) ^ (rn&7)))*8);
      }
      #pragma unroll
      for (int mi=0;mi<MI;mi++)
        #pragma unroll
        for (int ni=0;ni<NI;ni++)
          acc[mi][ni] = __builtin_amdgcn_mfma_f32_16x16x32_bf16(af[mi], bfr[ni], acc[mi][ni], 0,0,0);
    }
  }

  #pragma unroll
  for (int mi=0;mi<MI;mi++){
    const int grow0 = m0 + wm*64 + mi*16 + quad*4;
    #pragma unroll
    for (int ni=0;ni<NI;ni++){
      const int gcol = n0 + wn*(TN/2) + ni*16 + l16;
      const float bvx = bias[gcol];
      if constexpr (MODE==1){
        float* xo = (float*)out0;
        #pragma unroll
        for (int r=0;r<4;r++){
          size_t idx = (size_t)(grow0+r)*E_DIM + gcol;
          xo[idx] = resid[idx] + acc[mi][ni][r] + bvx;
        }
      } else if constexpr (MODE==2){
        bf16_t* hp = (bf16_t*)out0;
        #pragma unroll
        for (int r=0;r<4;r++)
          hp[(size_t)(grow0+r)*MLP_DIM + gcol] = (bf16_t)gelu_f(acc[mi][ni][r] + bvx);
      } else {
        float* xo = (float*)out0;
        #pragma unroll
        for (int r=0;r<4;r++){
          size_t idx = (size_t)(grow0+r)*E_DIM + gcol;
          xo[idx] = xo[idx] + acc[mi][ni][r] + bvx;
        }
      }
    }
  }
}

// ---------------- fused attention: one block = (b, 16 q-rows), loops 8 heads ----------------
// 512 threads (8 waves), amdgpu_waves_per_eu(2,2): LDS (135 KB) allows only
// 1 block/CU = 2 waves/SIMD, so pin that and claim the full 256-reg/wave
// budget (unified VGPR+AGPR file). Kills the scratch spills that plagued the
// 1024-thread version (capped at 64+64 regs).
// Softmax computed ONCE in pass 1.5 (each wave owns whole rows): gate-mult,
// butterfly sum/max (all lanes get result), e=exp stored back to LDS, z by
// butterfly -> no cross-wave reduce arrays, no zsh atomics, and passes 2/3
// just read e (exp count per element: 5 -> 1).
// Gate for head h+1 prefetched into regs before pass 3 (fits in 256 regs).
__global__ __launch_bounds__(512) __attribute__((amdgpu_waves_per_eu(2, 2)))
void attn_kernel(
    const bf16_t* __restrict__ qhb, const bf16_t* __restrict__ qlb,
    const bf16_t* __restrict__ khb, const bf16_t* __restrict__ klb,
    const bf16_t* __restrict__ vt,  const float* __restrict__ gate,
    bf16_t* __restrict__ og, float* __restrict__ aw)
{
  __shared__ __align__(16) float u_s[16*2048];   // 131072 B, f32x4-XOR swizzled
  __shared__ float osh[16*64];
  __shared__ float zsh[16];

  const int b   = blockIdx.x >> 7;
  const int sqt = blockIdx.x & 127;
  const int sq0 = sqt*16;

  const int tid = threadIdx.x;           // 0..511
  const int wave = tid>>6, lane = tid&63, quad = lane>>4, l16 = lane&15;

  float awacc[64];                       // 2 rows x 32 cols-quarters per thread
  #pragma unroll
  for (int j=0;j<64;j++) awacc[j] = 0.f;

  // gate prefetch for head 0: wave owns rows {wave*2, wave*2+1}
  f32x4 gpre[2][8];
  #pragma unroll
  for (int rr=0;rr<2;rr++){
    const float* gp = gate + ((size_t)(b*H_NUM)*S_LEN + sq0 + wave*2 + rr)*S_LEN + (size_t)lane*4;
    #pragma unroll
    for (int it=0; it<8; it++)
      gpre[rr][it] = __builtin_nontemporal_load((const f32x4*)(gp + it*256));
  }

  for (int h = 0; h < H_NUM; h++){
    const int bh = b*H_NUM + h;

    osh[tid] = 0.f; osh[tid + 512] = 0.f;

    bf16x8 qah0, qah1, qal0, qal1;
    {
      const size_t qoff = ((size_t)bh*S_LEN + sq0 + l16)*DH + quad*8;
      qah0 = *(const bf16x8*)(qhb + qoff);
      qah1 = *(const bf16x8*)(qhb + qoff + 32);
      qal0 = *(const bf16x8*)(qlb + qoff);
      qal1 = *(const bf16x8*)(qlb + qoff + 32);
    }

    // ---- pass 1: raw scores s = q.k^T -> swizzled LDS
    for (int cb = wave; cb < 32; cb += 8){
      #pragma unroll
      for (int nb=0; nb<4; nb++){
        const int col0 = cb*64 + nb*16;
        const size_t koff = ((size_t)bh*S_LEN + col0 + l16)*DH + quad*8;
        bf16x8 khf0 = *(const bf16x8*)(khb + koff);
        bf16x8 khf1 = *(const bf16x8*)(khb + koff + 32);
        bf16x8 klf0 = *(const bf16x8*)(klb + koff);
        bf16x8 klf1 = *(const bf16x8*)(klb + koff + 32);
        f32x4 acc = (f32x4){0.f,0.f,0.f,0.f};
        acc = __builtin_amdgcn_mfma_f32_16x16x32_bf16(qah0, khf0, acc, 0,0,0);
        acc = __builtin_amdgcn_mfma_f32_16x16x32_bf16(qah1, khf1, acc, 0,0,0);
        acc = __builtin_amdgcn_mfma_f32_16x16x32_bf16(qal0, khf0, acc, 0,0,0);
        acc = __builtin_amdgcn_mfma_f32_16x16x32_bf16(qal1, khf1, acc, 0,0,0);
        acc = __builtin_amdgcn_mfma_f32_16x16x32_bf16(qah0, klf0, acc, 0,0,0);
        acc = __builtin_amdgcn_mfma_f32_16x16x32_bf16(qah1, klf1, acc, 0,0,0);
        const int c = col0 + l16;
        #pragma unroll
        for (int r=0;r<4;r++){
          const int row = quad*4 + r;
          u_s[row*2048 + (c ^ ((row&7)<<2))] = acc[r];
        }
      }
    }
    __syncthreads();

    // ---- pass 1.5: full softmax per row, one wave = 2 rows, all in-wave.
    // u = s*gate (gate from regs); butterfly fp64 sum + max/min (all lanes get
    // result); e = exp(u*inv - m) stored back to LDS; z butterfly -> zsh[row].
    #pragma unroll
    for (int rr=0; rr<2; rr++){
      const int row = wave*2 + rr;
      f32x4* ub = (f32x4*)u_s + (size_t)row*512;
      const int sw = row & 7;
      f32x4 uv[8];
      double s = 0.0;
      float mx = -__builtin_inff(), mn = __builtin_inff();
      #pragma unroll
      for (int it=0; it<8; it++){
        uv[it] = ub[(it*64 + lane) ^ sw] * gpre[rr][it];
        s += ((double)uv[it][0] + (double)uv[it][1]) + ((double)uv[it][2] + (double)uv[it][3]);
        mx = fmaxf(mx, fmaxf(fmaxf(uv[it][0],uv[it][1]), fmaxf(uv[it][2],uv[it][3])));
        mn = fminf(mn, fminf(fminf(uv[it][0],uv[it][1]), fminf(uv[it][2],uv[it][3])));
      }
      #pragma unroll
      for (int off=1; off<64; off<<=1){
        s  += __shfl_xor(s, off, 64);
        mx = fmaxf(mx, __shfl_xor(mx, off, 64));
        mn = fminf(mn, __shfl_xor(mn, off, 64));
      }
      const double rsum = s + 1e-12;
      const float inv = (float)(1.0/rsum);
      const float m = (rsum > 0.0 ? mx : mn) * inv;   // exact max of u*inv -> max e == 1
      float z = 0.f;
      #pragma unroll
      for (int it=0; it<8; it++){
        f32x4 e;
        e[0] = __expf(uv[it][0]*inv - m);
        e[1] = __expf(uv[it][1]*inv - m);
        e[2] = __expf(uv[it][2]*inv - m);
        e[3] = __expf(uv[it][3]*inv - m);
        ub[(it*64 + lane) ^ sw] = e;
        z += (e[0]+e[1]) + (e[2]+e[3]);
      }
      #pragma unroll
      for (int off=1; off<64; off<<=1) z += __shfl_xor(z, off, 64);
      if (lane == 0) zsh[row] = z;
    }
    __syncthreads();

    // ---- pass 2: o = e @ V  (8 waves: nb2 x k-half; e read straight from LDS)
    {
      const int nb2 = wave & 3, khh = wave >> 2;
      f32x4 oacc = (f32x4){0.f,0.f,0.f,0.f};
      const bf16_t* vbase = vt + ((size_t)bh*DH + nb2*16 + l16)*S_LEN;
      const f32x4* ur4 = (const f32x4*)u_s + (size_t)l16*512;
      const int swr = l16 & 7;
      #pragma unroll 4
      for (int kc = khh*32; kc < khh*32 + 32; kc++){
        const int c4a = kc*8 + quad*2;
        f32x4 e0 = ur4[c4a ^ swr];
        f32x4 e1 = ur4[(c4a+1) ^ swr];
        bf16x8 pa;
        pa[0]=(bf16_t)e0[0]; pa[1]=(bf16_t)e0[1]; pa[2]=(bf16_t)e0[2]; pa[3]=(bf16_t)e0[3];
        pa[4]=(bf16_t)e1[0]; pa[5]=(bf16_t)e1[1]; pa[6]=(bf16_t)e1[2]; pa[7]=(bf16_t)e1[3];
        bf16x8 vf = *(const bf16x8*)(vbase + kc*32 + quad*8);
        oacc = __builtin_amdgcn_mfma_f32_16x16x32_bf16(pa, vf, oacc, 0,0,0);
      }
      #pragma unroll
      for (int r=0;r<4;r++)
        atomicAdd(&osh[(quad*4+r)*64 + nb2*16 + l16], oacc[r]);
    }
    __syncthreads();

    // ---- epilogue: o/z gathered to (B, t, E) layout for out-proj
    #pragma unroll
    for (int t = tid; t < 1024; t += 512){
      int r = t >> 6, d = t & 63;
      float val = osh[t] / zsh[r];
      og[((size_t)(b*S_LEN + sq0 + r))*E_DIM + h*DH + d] = (bf16_t)val;
    }

    // ---- prefetch gate for next head (consumed in next pass 1.5; latency
    // hidden under pass 3 + next pass 1)
    if (h + 1 < H_NUM){
      #pragma unroll
      for (int rr=0;rr<2;rr++){
        const float* gp = gate + ((size_t)(b*H_NUM + h + 1)*S_LEN + sq0 + wave*2 + rr)*S_LEN + (size_t)lane*4;
        #pragma unroll
        for (int it=0; it<8; it++)
          gpre[rr][it] = __builtin_nontemporal_load((const f32x4*)(gp + it*256));
      }
    }

    // ---- pass 3: accumulate head-mean attention weights in registers (e from LDS)
    #pragma unroll
    for (int rr=0; rr<2; rr++){
      const int row = wave*2 + rr;
      const float sc = 0.125f / zsh[row];
      const f32x4* ur3 = (const f32x4*)u_s + (size_t)row*512;
      const int sw3 = row & 7;
      #pragma unroll
      for (int g=0; g<8; g++){
        f32x4 e = ur3[(g*64 + lane) ^ sw3];
        awacc[rr*32+g*4+0] = fmaf(e[0], sc, awacc[rr*32+g*4+0]);
        awacc[rr*32+g*4+1] = fmaf(e[1], sc, awacc[rr*32+g*4+1]);
        awacc[rr*32+g*4+2] = fmaf(e[2], sc, awacc[rr*32+g*4+2]);
        awacc[rr*32+g*4+3] = fmaf(e[3], sc, awacc[rr*32+g*4+3]);
      }
    }
    __syncthreads();   // protect u_s / osh / zsh for next head
  }

  // ---- coalesced aw write: 2 rows x 8 f32x4 NT stores per thread
  #pragma unroll
  for (int rr=0; rr<2; rr++){
    float* awrow = aw + ((size_t)(b*S_LEN) + sq0 + wave*2 + rr)*S_LEN + (size_t)lane*4;
    #pragma unroll
    for (int g=0; g<8; g++){
      f32x4 v = (f32x4){ awacc[rr*32+g*4+0], awacc[rr*32+g*4+1],
                         awacc[rr*32+g*4+2], awacc[rr*32+g*4+3] };
      __builtin_nontemporal_store(v, (f32x4*)(awrow + g*256));
    }
  }
}

// ---------------- launch ----------------
extern "C" void kernel_launch(void* const* d_in, const int* in_sizes, int n_in,
                              void* d_out, int out_size, void* d_ws, size_t ws_size,
                              hipStream_t stream)
{
  const float* query     = (const float*)d_in[0];
  const float* gate      = (const float*)d_in[1];
  const float* in_proj_w = (const float*)d_in[2];
  const float* in_proj_b = (const float*)d_in[3];
  const float* out_w     = (const float*)d_in[4];
  const float* out_b     = (const float*)d_in[5];
  const float* ln1_w     = (const float*)d_in[6];
  const float* ln1_b     = (const float*)d_in[7];
  const float* ln2_w     = (const float*)d_in[8];
  const float* ln2_b     = (const float*)d_in[9];
  const float* w1        = (const float*)d_in[10];
  const float* b1        = (const float*)d_in[11];
  const float* w2        = (const float*)d_in[12];
  const float* b2        = (const float*)d_in[13];

  char* ws = (char*)d_ws;
  bf16_t* nqh   = (bf16_t*)(ws);                    // 4 MB
  bf16_t* nql   = (bf16_t*)(ws + ((size_t)4<<20));  // 4 MB
  bf16_t* qh    = (bf16_t*)(ws + ((size_t)8<<20));  // 4 MB
  bf16_t* ql    = (bf16_t*)(ws + ((size_t)12<<20)); // 4 MB
  bf16_t* kh    = (bf16_t*)(ws + ((size_t)16<<20)); // 4 MB
  bf16_t* kl    = (bf16_t*)(ws + ((size_t)20<<20)); // 4 MB
  bf16_t* vtmp  = (bf16_t*)(ws + ((size_t)24<<20)); // 4 MB
  bf16_t* vt    = (bf16_t*)(ws + ((size_t)28<<20)); // 4 MB
  bf16_t* og    = (bf16_t*)(ws + ((size_t)32<<20)); // 4 MB
  bf16_t* hmid  = (bf16_t*)(ws + ((size_t)36<<20)); // 4 MB
  bf16_t* h1    = (bf16_t*)(ws + ((size_t)40<<20)); // 16 MB
  bf16_t* wqh   = (bf16_t*)(ws + ((size_t)56<<20)); // 1.5 MB
  bf16_t* wql   = (bf16_t*)(ws + ((size_t)58<<20)); // 1.5 MB
  bf16_t* woutb = (bf16_t*)(ws + ((size_t)60<<20)); // 0.5 MB
  bf16_t* w1b   = (bf16_t*)(ws + ((size_t)61<<20)); // 2 MB
  bf16_t* w2b   = (bf16_t*)(ws + ((size_t)63<<20)); // 2 MB

  float* xout = (float*)d_out;                       // (B,S,E) fp32
  float* aw   = xout + (size_t)2*S_LEN*E_DIM;        // (B,S,S) fp32

  cvt_split_kernel<<<768, 256, 0, stream>>>(in_proj_w, wqh, wql, 786432);
  cvt_kernel<<<256, 256, 0, stream>>>(out_w, woutb, 262144);
  cvt_kernel<<<1024,256, 0, stream>>>(w1,    w1b,   1048576);
  cvt_kernel<<<1024,256, 0, stream>>>(w2,    w2b,   1048576);

  // ln1(query) -> split nq
  ln_split_kernel<<<1024, 256, 0, stream>>>(query, ln1_w, ln1_b, nqh, nql);

  // qkv split GEMM: q,k as hi/lo pairs; v plain flat
  gemm_qkv_split<<<768, 256, 0, stream>>>(nqh, nql, wqh, wql, in_proj_b,
                                          qh, ql, kh, kl, vtmp);

  // v -> vt[i][d][t] (raw-reshape pseudo-head transpose)
  vtrans_kernel<<<128, 256, 0, stream>>>(vtmp, vt);

  // fused gated-renorm softmax attention: 256 blocks x 512 threads
  attn_kernel<<<256, 512, 0, stream>>>(qh, ql, kh, kl, vt, gate, og, aw);

  // x = query + og @ out_w^T + out_b   (fp32 -> d_out)
  gemm_kernel<64,1><<<256, 256, 0, stream>>>(og, woutb, out_b,
      4096, 512, 512, (void*)xout, query);

  // hmid = ln2(x)
  ln_kernel<<<1024, 256, 0, stream>>>(xout, ln2_w, ln2_b, hmid);

  // h1 = gelu(hmid @ w1^T + b1)
  gemm_kernel<128,2><<<512, 256, 0, stream>>>(hmid, w1b, b1,
      4096, 2048, 512, (void*)h1, nullptr);

  // x += h1 @ w2^T + b2
  gemm_kernel<64,3><<<256, 256, 0, stream>>>(h1, w2b, b2,
      4096, 512, 2048, (void*)xout, nullptr);
}